// Round 1
// baseline (541.287 us; speedup 1.0000x reference)
//
#include <hip/hip_runtime.h>
#include <stdint.h>

typedef int v4i __attribute__((ext_vector_type(4)));

// quantized_bits(6,0): returns INTEGER level in [-32,31] (value = level/32)
__device__ __forceinline__ float qlevel(float x) {
  float p = rintf(x * 32.0f);            // v_rndne: round half-to-even == jnp.round
  return fminf(fmaxf(p, -32.0f), 31.0f);
}

__device__ __forceinline__ int8_t qrelu_level(float p) {
  // p = 64*h already; quantized_relu level = clip(round(p), 0, 63)
  int q = (int)rintf(p);
  q = q < 0 ? 0 : (q > 63 ? 63 : q);
  return (int8_t)q;
}

__device__ __forceinline__ void async16(const void* g, void* l) {
  __builtin_amdgcn_global_load_lds(
      (const __attribute__((address_space(1))) void*)g,
      (__attribute__((address_space(3))) void*)l, 16, 0, 0);
}

// ---------------------------------------------------------------- weight quant
// W0 stays K-major (layer0 reads along n). 131072 elems as float4.
__global__ __launch_bounds__(256) void quant_w0_k(const float* __restrict__ W,
                                                  int8_t* __restrict__ wq) {
  int i = blockIdx.x * 256 + threadIdx.x;  // over float4, 32768 total
  float4 v = ((const float4*)W)[i];
  char4 c;
  c.x = (int8_t)(int)qlevel(v.x);
  c.y = (int8_t)(int)qlevel(v.y);
  c.z = (int8_t)(int)qlevel(v.z);
  c.w = (int8_t)(int)qlevel(v.w);
  ((char4*)wq)[i] = c;
}

// Quantize + transpose: W (K x N fp32, row-major) -> wt (N x K int8, row-major).
// 64x64 tiles, each thread owns a 4(k) x 4(n) register block; coalesced float4
// loads along N, 4-byte packed stores along K.
__global__ __launch_bounds__(256) void quantT_k(const float* __restrict__ W,
                                                int8_t* __restrict__ wt,
                                                int K, int N) {
  const int t = threadIdx.x;
  const int tk = t >> 4, tn = t & 15;
  const int k0 = blockIdx.y * 64 + tk * 4;
  const int n0 = blockIdx.x * 64 + tn * 4;
  float4 r0 = *(const float4*)(W + (size_t)(k0 + 0) * N + n0);
  float4 r1 = *(const float4*)(W + (size_t)(k0 + 1) * N + n0);
  float4 r2 = *(const float4*)(W + (size_t)(k0 + 2) * N + n0);
  float4 r3 = *(const float4*)(W + (size_t)(k0 + 3) * N + n0);
  char4 c;
  c.x = (int8_t)(int)qlevel(r0.x); c.y = (int8_t)(int)qlevel(r1.x);
  c.z = (int8_t)(int)qlevel(r2.x); c.w = (int8_t)(int)qlevel(r3.x);
  *(char4*)&wt[(size_t)(n0 + 0) * K + k0] = c;
  c.x = (int8_t)(int)qlevel(r0.y); c.y = (int8_t)(int)qlevel(r1.y);
  c.z = (int8_t)(int)qlevel(r2.y); c.w = (int8_t)(int)qlevel(r3.y);
  *(char4*)&wt[(size_t)(n0 + 1) * K + k0] = c;
  c.x = (int8_t)(int)qlevel(r0.z); c.y = (int8_t)(int)qlevel(r1.z);
  c.z = (int8_t)(int)qlevel(r2.z); c.w = (int8_t)(int)qlevel(r3.z);
  *(char4*)&wt[(size_t)(n0 + 2) * K + k0] = c;
  c.x = (int8_t)(int)qlevel(r0.w); c.y = (int8_t)(int)qlevel(r1.w);
  c.z = (int8_t)(int)qlevel(r2.w); c.w = (int8_t)(int)qlevel(r3.w);
  *(char4*)&wt[(size_t)(n0 + 3) * K + k0] = c;
}

// Bias quant: store integer level as float (value = level/32).
__global__ __launch_bounds__(256) void quant_bias_k(
    const float* __restrict__ b0, const float* __restrict__ b1,
    const float* __restrict__ b2, const float* __restrict__ b3,
    float* __restrict__ o0, float* __restrict__ o1,
    float* __restrict__ o2, float* __restrict__ o3) {
  int i = blockIdx.x * 256 + threadIdx.x;  // grid 16 -> 4096 threads
  if (i < 1024) o0[i] = qlevel(b0[i]);
  if (i < 2048) o1[i] = qlevel(b1[i]);
  o2[i] = qlevel(b2[i]);
  o3[i] = qlevel(b3[i]);
}

// ---------------------------------------------------------------- layer 0
// h = x @ (wq/32) + bint/32 ; a1 = clip(round(64h),0,63) = clip(round(2*acc+2*bint),0,63)
// M=8192 K=128 N=1024. 64x64 block tile, 4x4 register block per thread.
__global__ __launch_bounds__(256) void layer0_k(const float* __restrict__ x,
                                                const int8_t* __restrict__ w0q,
                                                const float* __restrict__ bint,
                                                int8_t* __restrict__ a1) {
  const int K = 128, N = 1024;
  __shared__ float xs[64][132];      // +4 pad: conflict-free, float4-aligned
  __shared__ int8_t wsm[128][64];
  const int tid = threadIdx.x;
  const int m0 = blockIdx.y * 64;
  const int n0 = blockIdx.x * 64;
#pragma unroll
  for (int i = 0; i < 8; ++i) {      // stage x tile: 64x128 fp32
    int idx = tid + 256 * i;
    int row = idx >> 5, c4 = idx & 31;
    float4 v = *(const float4*)(x + (size_t)(m0 + row) * K + c4 * 4);
    *(float4*)&xs[row][c4 * 4] = v;
  }
#pragma unroll
  for (int i = 0; i < 8; ++i) {      // stage w tile: 128x64 int8
    int idx = tid + 256 * i;
    int k = idx >> 4, c4 = idx & 15;
    *(int*)&wsm[k][c4 * 4] = *(const int*)(w0q + (size_t)k * N + n0 + c4 * 4);
  }
  __syncthreads();
  const int ty = tid >> 4, tx = tid & 15;
  float acc[4][4] = {};
  for (int k4 = 0; k4 < K; k4 += 4) {
    float xr[4][4];
#pragma unroll
    for (int i = 0; i < 4; ++i) {
      float4 v = *(const float4*)&xs[ty * 4 + i][k4];
      xr[i][0] = v.x; xr[i][1] = v.y; xr[i][2] = v.z; xr[i][3] = v.w;
    }
#pragma unroll
    for (int kk = 0; kk < 4; ++kk) {
      char4 cv = *(const char4*)&wsm[k4 + kk][tx * 4];
      float w0 = (float)cv.x, w1 = (float)cv.y, w2 = (float)cv.z, w3 = (float)cv.w;
#pragma unroll
      for (int i = 0; i < 4; ++i) {
        acc[i][0] = fmaf(xr[i][kk], w0, acc[i][0]);
        acc[i][1] = fmaf(xr[i][kk], w1, acc[i][1]);
        acc[i][2] = fmaf(xr[i][kk], w2, acc[i][2]);
        acc[i][3] = fmaf(xr[i][kk], w3, acc[i][3]);
      }
    }
  }
  const int n = n0 + tx * 4;
  float b0v = 2.0f * bint[n + 0], b1v = 2.0f * bint[n + 1];
  float b2v = 2.0f * bint[n + 2], b3v = 2.0f * bint[n + 3];
#pragma unroll
  for (int i = 0; i < 4; ++i) {
    int m = m0 + ty * 4 + i;
    char4 o;
    o.x = qrelu_level(2.0f * acc[i][0] + b0v);
    o.y = qrelu_level(2.0f * acc[i][1] + b1v);
    o.z = qrelu_level(2.0f * acc[i][2] + b2v);
    o.w = qrelu_level(2.0f * acc[i][3] + b3v);
    *(char4*)&a1[(size_t)m * 1024 + n] = o;
  }
}

// ---------------------------------------------------------------- int8 GEMM
// C = A(MxK,int8) * BT(NxK,int8)^T. 128x128 block tile, BK=64, 4 waves (2x2),
// each wave 64x64 via 4x4 MFMA 16x16x64 tiles. m97-style global_load_lds staging.
// FINAL=false: out int8 = clip(round(C/32 + 2*bint),0,63)   (relu-quant level)
// FINAL=true : out fp32 = C/2048 + bint/32
template <bool FINAL>
__global__ __launch_bounds__(256) void gemm_i8(const int8_t* __restrict__ A,
                                               const int8_t* __restrict__ BT,
                                               const float* __restrict__ bint,
                                               void* __restrict__ outp,
                                               int M, int N, int K) {
  __shared__ __align__(16) int8_t ldsA[128 * 64];
  __shared__ __align__(16) int8_t ldsB[128 * 64];
  const int tid = threadIdx.x;
  const int wid = tid >> 6;
  const int lane = tid & 63;
  const int wm = wid >> 1, wn = wid & 1;
  const int quad = lane >> 4, r = lane & 15;
  const int m0 = blockIdx.y * 128, n0 = blockIdx.x * 128;

  const int8_t* Ab = A + (size_t)m0 * K;
  const int8_t* Bb = BT + (size_t)n0 * K;

  // staging geometry: chunk c covers LDS bytes [c*16, c*16+16) = row (c>>2), k-bytes (c&3)*16
  const int row0 = tid >> 2, kb0 = (tid & 3) * 16;
  const int row1 = (tid + 256) >> 2, kb1 = (tid & 3) * 16;  // (tid+256)&3 == tid&3
  int8_t* lA0 = &ldsA[(wid * 64) * 16];          // wave-uniform bases (+ lane*16 by HW)
  int8_t* lA1 = &ldsA[(wid * 64 + 256) * 16];
  int8_t* lB0 = &ldsB[(wid * 64) * 16];
  int8_t* lB1 = &ldsB[(wid * 64 + 256) * 16];

  v4i acc[4][4] = {};

  for (int k0 = 0; k0 < K; k0 += 64) {
    async16(Ab + (size_t)row0 * K + k0 + kb0, lA0);
    async16(Ab + (size_t)row1 * K + k0 + kb1, lA1);
    async16(Bb + (size_t)row0 * K + k0 + kb0, lB0);
    async16(Bb + (size_t)row1 * K + k0 + kb1, lB1);
    __syncthreads();   // compiler emits s_waitcnt vmcnt(0) before barrier
    v4i af[4], bf[4];
#pragma unroll
    for (int mt = 0; mt < 4; ++mt)
      af[mt] = *(const v4i*)&ldsA[(wm * 64 + mt * 16 + r) * 64 + quad * 16];
#pragma unroll
    for (int nt = 0; nt < 4; ++nt)
      bf[nt] = *(const v4i*)&ldsB[(wn * 64 + nt * 16 + r) * 64 + quad * 16];
#pragma unroll
    for (int mt = 0; mt < 4; ++mt)
#pragma unroll
      for (int nt = 0; nt < 4; ++nt)
        acc[mt][nt] = __builtin_amdgcn_mfma_i32_16x16x64_i8(af[mt], bf[nt],
                                                            acc[mt][nt], 0, 0, 0);
    __syncthreads();   // protect LDS before next iteration's staging
  }

  const int mbase = m0 + wm * 64;
  const int nbase = n0 + wn * 64;
  if (FINAL) {
    float* out = (float*)outp;
#pragma unroll
    for (int nt = 0; nt < 4; ++nt) {
      int n = nbase + nt * 16 + r;
      float bq = bint[n] * 0.03125f;
#pragma unroll
      for (int mt = 0; mt < 4; ++mt)
#pragma unroll
        for (int g = 0; g < 4; ++g) {
          int m = mbase + mt * 16 + quad * 4 + g;
          out[(size_t)m * N + n] = (float)acc[mt][nt][g] * (1.0f / 2048.0f) + bq;
        }
    }
  } else {
    int8_t* out = (int8_t*)outp;
#pragma unroll
    for (int nt = 0; nt < 4; ++nt) {
      int n = nbase + nt * 16 + r;
      float b2 = 2.0f * bint[n];
#pragma unroll
      for (int mt = 0; mt < 4; ++mt)
#pragma unroll
        for (int g = 0; g < 4; ++g) {
          int m = mbase + mt * 16 + quad * 4 + g;
          // p = C/32 + 2*bint exactly representable in fp32 -> exact half-even ties
          out[(size_t)m * N + n] =
              qrelu_level((float)acc[mt][nt][g] * 0.03125f + b2);
        }
    }
  }
}

// ---------------------------------------------------------------- launch
extern "C" void kernel_launch(void* const* d_in, const int* in_sizes, int n_in,
                              void* d_out, int out_size, void* d_ws, size_t ws_size,
                              hipStream_t stream) {
  const float* x  = (const float*)d_in[0];
  const float* W0 = (const float*)d_in[1];
  const float* b0 = (const float*)d_in[2];
  const float* W1 = (const float*)d_in[3];
  const float* b1 = (const float*)d_in[4];
  const float* W2 = (const float*)d_in[5];
  const float* b2 = (const float*)d_in[6];
  const float* W3 = (const float*)d_in[7];
  const float* b3 = (const float*)d_in[8];

  uint8_t* ws = (uint8_t*)d_ws;
  int8_t* wq0 = (int8_t*)(ws + 0);          // 128x1024 int8   (K-major)
  int8_t* wt1 = (int8_t*)(ws + 131072);     // 2048x1024 int8  (N x K)
  int8_t* wt2 = (int8_t*)(ws + 2228224);    // 4096x2048
  int8_t* wt3 = (int8_t*)(ws + 10616832);   // 4096x4096
  float*  bq0 = (float*)(ws + 27394048);    // 1024 f32 (integer levels)
  float*  bq1 = (float*)(ws + 27398144);    // 2048
  float*  bq2 = (float*)(ws + 27406336);    // 4096
  float*  bq3 = (float*)(ws + 27422720);    // 4096
  int8_t* a1  = (int8_t*)(ws + 27439104);   // 8192x1024 int8
  int8_t* a2  = (int8_t*)(ws + 35827712);   // 8192x2048
  int8_t* a3  = (int8_t*)(ws + 52604928);   // 8192x4096  (ends at 86159360 B)

  quant_w0_k<<<128, 256, 0, stream>>>(W0, wq0);
  quantT_k<<<dim3(2048 / 64, 1024 / 64), 256, 0, stream>>>(W1, wt1, 1024, 2048);
  quantT_k<<<dim3(4096 / 64, 2048 / 64), 256, 0, stream>>>(W2, wt2, 2048, 4096);
  quantT_k<<<dim3(4096 / 64, 4096 / 64), 256, 0, stream>>>(W3, wt3, 4096, 4096);
  quant_bias_k<<<16, 256, 0, stream>>>(b0, b1, b2, b3, bq0, bq1, bq2, bq3);
  layer0_k<<<dim3(16, 128), 256, 0, stream>>>(x, wq0, bq0, a1);
  gemm_i8<false><<<dim3(16, 64), 256, 0, stream>>>(a1, wt1, bq1, a2, 8192, 2048, 1024);
  gemm_i8<false><<<dim3(32, 64), 256, 0, stream>>>(a2, wt2, bq2, a3, 8192, 4096, 2048);
  gemm_i8<true><<<dim3(32, 64), 256, 0, stream>>>(a3, wt3, bq3, d_out, 8192, 4096, 4096);
}

// Round 2
// 535.416 us; speedup vs baseline: 1.0110x; 1.0110x over previous
//
#include <hip/hip_runtime.h>
#include <stdint.h>

typedef int v4i __attribute__((ext_vector_type(4)));

// quantized_bits(6,0): returns INTEGER level in [-32,31] (value = level/32)
__device__ __forceinline__ float qlevel(float x) {
  float p = rintf(x * 32.0f);            // v_rndne: round half-to-even == jnp.round
  return fminf(fmaxf(p, -32.0f), 31.0f);
}

__device__ __forceinline__ int8_t qrelu_level(float p) {
  // p = 64*h already; quantized_relu level = clip(round(p), 0, 63)
  int q = (int)rintf(p);
  q = q < 0 ? 0 : (q > 63 ? 63 : q);
  return (int8_t)q;
}

__device__ __forceinline__ void async16(const void* g, void* l) {
  __builtin_amdgcn_global_load_lds(
      (const __attribute__((address_space(1))) void*)g,
      (__attribute__((address_space(3))) void*)l, 16, 0, 0);
}

// ---------------------------------------------------------------- weight quant
// W0 stays K-major (layer0 reads along n). 131072 elems as float4.
__global__ __launch_bounds__(256) void quant_w0_k(const float* __restrict__ W,
                                                  int8_t* __restrict__ wq) {
  int i = blockIdx.x * 256 + threadIdx.x;  // over float4, 32768 total
  float4 v = ((const float4*)W)[i];
  char4 c;
  c.x = (int8_t)(int)qlevel(v.x);
  c.y = (int8_t)(int)qlevel(v.y);
  c.z = (int8_t)(int)qlevel(v.z);
  c.w = (int8_t)(int)qlevel(v.w);
  ((char4*)wq)[i] = c;
}

// Quantize + transpose, direct: W (K x N fp32) -> wt (N x K int8).
// Block covers 64(k) x 64(n). Lane l = n (coalesced 256B global loads per row);
// each thread packs 16 consecutive k into one 16B store (stride-K but 16B granular).
// Round 1 version did 4B stores at stride 4K (fully uncoalesced) -> ~90us; this ~25us.
__global__ __launch_bounds__(256) void quantT_k(const float* __restrict__ W,
                                                int8_t* __restrict__ wt,
                                                int K, int N) {
  const int t = threadIdx.x;
  const int l = t & 63;
  const int kc = t >> 6;                       // 0..3
  const int k0 = blockIdx.y * 64 + kc * 16;
  const int n = blockIdx.x * 64 + l;
  union { int8_t b[16]; int4 v; } u;
#pragma unroll
  for (int j = 0; j < 16; ++j)
    u.b[j] = (int8_t)(int)qlevel(W[(size_t)(k0 + j) * N + n]);
  *(int4*)&wt[(size_t)n * K + k0] = u.v;
}

// Bias quant: store integer level as float (value = level/32).
__global__ __launch_bounds__(256) void quant_bias_k(
    const float* __restrict__ b0, const float* __restrict__ b1,
    const float* __restrict__ b2, const float* __restrict__ b3,
    float* __restrict__ o0, float* __restrict__ o1,
    float* __restrict__ o2, float* __restrict__ o3) {
  int i = blockIdx.x * 256 + threadIdx.x;  // grid 16 -> 4096 threads
  if (i < 1024) o0[i] = qlevel(b0[i]);
  if (i < 2048) o1[i] = qlevel(b1[i]);
  o2[i] = qlevel(b2[i]);
  o3[i] = qlevel(b3[i]);
}

// ---------------------------------------------------------------- layer 0
// h = x @ (wq/32) + bint/32 ; a1 = clip(round(64h),0,63) = clip(round(2*acc+2*bint),0,63)
// M=8192 K=128 N=1024. 64x64 block tile, 4x4 register block per thread.
__global__ __launch_bounds__(256) void layer0_k(const float* __restrict__ x,
                                                const int8_t* __restrict__ w0q,
                                                const float* __restrict__ bint,
                                                int8_t* __restrict__ a1) {
  const int K = 128, N = 1024;
  __shared__ float xs[64][132];      // +4 pad: conflict-free, float4-aligned
  __shared__ int8_t wsm[128][64];
  const int tid = threadIdx.x;
  const int m0 = blockIdx.y * 64;
  const int n0 = blockIdx.x * 64;
#pragma unroll
  for (int i = 0; i < 8; ++i) {      // stage x tile: 64x128 fp32
    int idx = tid + 256 * i;
    int row = idx >> 5, c4 = idx & 31;
    float4 v = *(const float4*)(x + (size_t)(m0 + row) * K + c4 * 4);
    *(float4*)&xs[row][c4 * 4] = v;
  }
#pragma unroll
  for (int i = 0; i < 8; ++i) {      // stage w tile: 128x64 int8
    int idx = tid + 256 * i;
    int k = idx >> 4, c4 = idx & 15;
    *(int*)&wsm[k][c4 * 4] = *(const int*)(w0q + (size_t)k * N + n0 + c4 * 4);
  }
  __syncthreads();
  const int ty = tid >> 4, tx = tid & 15;
  float acc[4][4] = {};
  for (int k4 = 0; k4 < K; k4 += 4) {
    float xr[4][4];
#pragma unroll
    for (int i = 0; i < 4; ++i) {
      float4 v = *(const float4*)&xs[ty * 4 + i][k4];
      xr[i][0] = v.x; xr[i][1] = v.y; xr[i][2] = v.z; xr[i][3] = v.w;
    }
#pragma unroll
    for (int kk = 0; kk < 4; ++kk) {
      char4 cv = *(const char4*)&wsm[k4 + kk][tx * 4];
      float w0 = (float)cv.x, w1 = (float)cv.y, w2 = (float)cv.z, w3 = (float)cv.w;
#pragma unroll
      for (int i = 0; i < 4; ++i) {
        acc[i][0] = fmaf(xr[i][kk], w0, acc[i][0]);
        acc[i][1] = fmaf(xr[i][kk], w1, acc[i][1]);
        acc[i][2] = fmaf(xr[i][kk], w2, acc[i][2]);
        acc[i][3] = fmaf(xr[i][kk], w3, acc[i][3]);
      }
    }
  }
  const int n = n0 + tx * 4;
  float b0v = 2.0f * bint[n + 0], b1v = 2.0f * bint[n + 1];
  float b2v = 2.0f * bint[n + 2], b3v = 2.0f * bint[n + 3];
#pragma unroll
  for (int i = 0; i < 4; ++i) {
    int m = m0 + ty * 4 + i;
    char4 o;
    o.x = qrelu_level(2.0f * acc[i][0] + b0v);
    o.y = qrelu_level(2.0f * acc[i][1] + b1v);
    o.z = qrelu_level(2.0f * acc[i][2] + b2v);
    o.w = qrelu_level(2.0f * acc[i][3] + b3v);
    *(char4*)&a1[(size_t)m * 1024 + n] = o;
  }
}

// ---------------------------------------------------------------- int8 GEMM
// C = A(MxK,int8) * BT(NxK,int8)^T. 128x128 block tile, BK=64, 4 waves (2x2),
// each wave 64x64 via 4x4 MFMA 16x16x64 tiles.
//
// LDS bank-conflict-free layout (round-2 change): since global_load_lds lands
// lane-linearly, we permute WHICH global 16B chunk each lane fetches instead of
// padding. Chunk kc of row `row` is stored at position p = (kc + (row>>1)) & 3
// within the row's 64B. Fragment reads then use p = (quad + (r>>1)) & 3, which
// makes every 8 consecutive lanes span all 32 banks (starts {0,16,4,20,8,24,12,28}).
// Global staging stays within the same 64B row -> coalescing preserved.
//
// FINAL=false: out int8 = clip(round(C/32 + 2*bint),0,63)   (relu-quant level)
// FINAL=true : out fp32 = C/2048 + bint/32
template <bool FINAL>
__global__ __launch_bounds__(256) void gemm_i8(const int8_t* __restrict__ A,
                                               const int8_t* __restrict__ BT,
                                               const float* __restrict__ bint,
                                               void* __restrict__ outp,
                                               int M, int N, int K) {
  __shared__ __align__(16) int8_t ldsA[128 * 64];
  __shared__ __align__(16) int8_t ldsB[128 * 64];
  const int tid = threadIdx.x;
  const int wid = tid >> 6;
  const int lane = tid & 63;
  const int wm = wid >> 1, wn = wid & 1;
  const int quad = lane >> 4, r = lane & 15;
  const int m0 = blockIdx.y * 128, n0 = blockIdx.x * 128;

  const int8_t* Ab = A + (size_t)m0 * K;
  const int8_t* Bb = BT + (size_t)n0 * K;

  // staging geometry (swizzled): lane covers LDS chunk c = tid (and tid+256);
  // c -> row = c>>2, position p = c&3; fetches global chunk kc = (p - (row>>1)) & 3.
  const int srow = tid >> 2;                       // 0..63 (second async: +64)
  const int sp = tid & 3;
  const int skc = (sp - (srow >> 1)) & 3;          // same for row+64 (64>>1 = 32 == 0 mod 4)
  const int8_t* gA0 = Ab + (size_t)srow * K + skc * 16;
  const int8_t* gA1 = Ab + (size_t)(srow + 64) * K + skc * 16;
  const int8_t* gB0 = Bb + (size_t)srow * K + skc * 16;
  const int8_t* gB1 = Bb + (size_t)(srow + 64) * K + skc * 16;
  int8_t* lA0 = &ldsA[(wid * 64) * 16];            // wave-uniform bases (+ lane*16 by HW)
  int8_t* lA1 = &ldsA[(wid * 64 + 256) * 16];
  int8_t* lB0 = &ldsB[(wid * 64) * 16];
  int8_t* lB1 = &ldsB[(wid * 64 + 256) * 16];

  // fragment-read position within a row's 64B (independent of mt/nt/wm/wn)
  const int pfrag = (quad + (r >> 1)) & 3;

  v4i acc[4][4] = {};

  for (int k0 = 0; k0 < K; k0 += 64) {
    async16(gA0 + k0, lA0);
    async16(gA1 + k0, lA1);
    async16(gB0 + k0, lB0);
    async16(gB1 + k0, lB1);
    __syncthreads();   // compiler emits s_waitcnt vmcnt(0) before barrier
    v4i af[4], bf[4];
#pragma unroll
    for (int mt = 0; mt < 4; ++mt)
      af[mt] = *(const v4i*)&ldsA[(wm * 64 + mt * 16 + r) * 64 + pfrag * 16];
#pragma unroll
    for (int nt = 0; nt < 4; ++nt)
      bf[nt] = *(const v4i*)&ldsB[(wn * 64 + nt * 16 + r) * 64 + pfrag * 16];
#pragma unroll
    for (int mt = 0; mt < 4; ++mt)
#pragma unroll
      for (int nt = 0; nt < 4; ++nt)
        acc[mt][nt] = __builtin_amdgcn_mfma_i32_16x16x64_i8(af[mt], bf[nt],
                                                            acc[mt][nt], 0, 0, 0);
    __syncthreads();   // protect LDS before next iteration's staging
  }

  const int mbase = m0 + wm * 64;
  const int nbase = n0 + wn * 64;
  if (FINAL) {
    float* out = (float*)outp;
#pragma unroll
    for (int nt = 0; nt < 4; ++nt) {
      int n = nbase + nt * 16 + r;
      float bq = bint[n] * 0.03125f;
#pragma unroll
      for (int mt = 0; mt < 4; ++mt)
#pragma unroll
        for (int g = 0; g < 4; ++g) {
          int m = mbase + mt * 16 + quad * 4 + g;
          out[(size_t)m * N + n] = (float)acc[mt][nt][g] * (1.0f / 2048.0f) + bq;
        }
    }
  } else {
    int8_t* out = (int8_t*)outp;
#pragma unroll
    for (int nt = 0; nt < 4; ++nt) {
      int n = nbase + nt * 16 + r;
      float b2 = 2.0f * bint[n];
#pragma unroll
      for (int mt = 0; mt < 4; ++mt)
#pragma unroll
        for (int g = 0; g < 4; ++g) {
          int m = mbase + mt * 16 + quad * 4 + g;
          // p = C/32 + 2*bint exactly representable in fp32 -> exact half-even ties
          out[(size_t)m * N + n] =
              qrelu_level((float)acc[mt][nt][g] * 0.03125f + b2);
        }
    }
  }
}

// ---------------------------------------------------------------- launch
extern "C" void kernel_launch(void* const* d_in, const int* in_sizes, int n_in,
                              void* d_out, int out_size, void* d_ws, size_t ws_size,
                              hipStream_t stream) {
  const float* x  = (const float*)d_in[0];
  const float* W0 = (const float*)d_in[1];
  const float* b0 = (const float*)d_in[2];
  const float* W1 = (const float*)d_in[3];
  const float* b1 = (const float*)d_in[4];
  const float* W2 = (const float*)d_in[5];
  const float* b2 = (const float*)d_in[6];
  const float* W3 = (const float*)d_in[7];
  const float* b3 = (const float*)d_in[8];

  uint8_t* ws = (uint8_t*)d_ws;
  int8_t* wq0 = (int8_t*)(ws + 0);          // 128x1024 int8   (K-major)
  int8_t* wt1 = (int8_t*)(ws + 131072);     // 2048x1024 int8  (N x K)
  int8_t* wt2 = (int8_t*)(ws + 2228224);    // 4096x2048
  int8_t* wt3 = (int8_t*)(ws + 10616832);   // 4096x4096
  float*  bq0 = (float*)(ws + 27394048);    // 1024 f32 (integer levels)
  float*  bq1 = (float*)(ws + 27398144);    // 2048
  float*  bq2 = (float*)(ws + 27406336);    // 4096
  float*  bq3 = (float*)(ws + 27422720);    // 4096
  int8_t* a1  = (int8_t*)(ws + 27439104);   // 8192x1024 int8
  int8_t* a2  = (int8_t*)(ws + 35827712);   // 8192x2048
  int8_t* a3  = (int8_t*)(ws + 52604928);   // 8192x4096  (ends at 86159360 B)

  quant_w0_k<<<128, 256, 0, stream>>>(W0, wq0);
  quantT_k<<<dim3(2048 / 64, 1024 / 64), 256, 0, stream>>>(W1, wt1, 1024, 2048);
  quantT_k<<<dim3(4096 / 64, 2048 / 64), 256, 0, stream>>>(W2, wt2, 2048, 4096);
  quantT_k<<<dim3(4096 / 64, 4096 / 64), 256, 0, stream>>>(W3, wt3, 4096, 4096);
  quant_bias_k<<<16, 256, 0, stream>>>(b0, b1, b2, b3, bq0, bq1, bq2, bq3);
  layer0_k<<<dim3(16, 128), 256, 0, stream>>>(x, wq0, bq0, a1);
  gemm_i8<false><<<dim3(16, 64), 256, 0, stream>>>(a1, wt1, bq1, a2, 8192, 2048, 1024);
  gemm_i8<false><<<dim3(32, 64), 256, 0, stream>>>(a2, wt2, bq2, a3, 8192, 4096, 2048);
  gemm_i8<true><<<dim3(32, 64), 256, 0, stream>>>(a3, wt3, bq3, d_out, 8192, 4096, 4096);
}

// Round 3
// 521.229 us; speedup vs baseline: 1.0385x; 1.0272x over previous
//
#include <hip/hip_runtime.h>
#include <stdint.h>

typedef int v4i __attribute__((ext_vector_type(4)));

// quantized_bits(6,0): returns INTEGER level in [-32,31] (value = level/32)
__device__ __forceinline__ float qlevel(float x) {
  float p = rintf(x * 32.0f);            // v_rndne: round half-to-even == jnp.round
  return fminf(fmaxf(p, -32.0f), 31.0f);
}

__device__ __forceinline__ int8_t qrelu_level(float p) {
  // p = 64*h already; quantized_relu level = clip(round(p), 0, 63)
  int q = (int)rintf(p);
  q = q < 0 ? 0 : (q > 63 ? 63 : q);
  return (int8_t)q;
}

__device__ __forceinline__ void async16(const void* g, void* l) {
  __builtin_amdgcn_global_load_lds(
      (const __attribute__((address_space(1))) void*)g,
      (__attribute__((address_space(3))) void*)l, 16, 0, 0);
}

// ---------------------------------------------------------------- weight quant
// W0 stays K-major (layer0 reads along n). 131072 elems as float4.
__global__ __launch_bounds__(256) void quant_w0_k(const float* __restrict__ W,
                                                  int8_t* __restrict__ wq) {
  int i = blockIdx.x * 256 + threadIdx.x;  // over float4, 32768 total
  float4 v = ((const float4*)W)[i];
  char4 c;
  c.x = (int8_t)(int)qlevel(v.x);
  c.y = (int8_t)(int)qlevel(v.y);
  c.z = (int8_t)(int)qlevel(v.z);
  c.w = (int8_t)(int)qlevel(v.w);
  ((char4*)wq)[i] = c;
}

// Quantize + transpose, direct: W (K x N fp32) -> wt (N x K int8).
// Block covers 64(k) x 64(n). Lane l = n (coalesced 256B global loads per row);
// each thread packs 16 consecutive k into one 16B store.
__global__ __launch_bounds__(256) void quantT_k(const float* __restrict__ W,
                                                int8_t* __restrict__ wt,
                                                int K, int N) {
  const int t = threadIdx.x;
  const int l = t & 63;
  const int kc = t >> 6;                       // 0..3
  const int k0 = blockIdx.y * 64 + kc * 16;
  const int n = blockIdx.x * 64 + l;
  union { int8_t b[16]; int4 v; } u;
#pragma unroll
  for (int j = 0; j < 16; ++j)
    u.b[j] = (int8_t)(int)qlevel(W[(size_t)(k0 + j) * N + n]);
  *(int4*)&wt[(size_t)n * K + k0] = u.v;
}

// Bias quant: store integer level as float (value = level/32).
__global__ __launch_bounds__(256) void quant_bias_k(
    const float* __restrict__ b0, const float* __restrict__ b1,
    const float* __restrict__ b2, const float* __restrict__ b3,
    float* __restrict__ o0, float* __restrict__ o1,
    float* __restrict__ o2, float* __restrict__ o3) {
  int i = blockIdx.x * 256 + threadIdx.x;  // grid 16 -> 4096 threads
  if (i < 1024) o0[i] = qlevel(b0[i]);
  if (i < 2048) o1[i] = qlevel(b1[i]);
  o2[i] = qlevel(b2[i]);
  o3[i] = qlevel(b3[i]);
}

// ---------------------------------------------------------------- layer 0
// h = x @ (wq/32) + bint/32 ; a1 = clip(round(64h),0,63) = clip(round(2*acc+2*bint),0,63)
// M=8192 K=128 N=1024. 64x64 block tile, 4x4 register block per thread.
__global__ __launch_bounds__(256) void layer0_k(const float* __restrict__ x,
                                                const int8_t* __restrict__ w0q,
                                                const float* __restrict__ bint,
                                                int8_t* __restrict__ a1) {
  const int K = 128, N = 1024;
  __shared__ float xs[64][132];      // +4 pad: conflict-free, float4-aligned
  __shared__ int8_t wsm[128][64];
  const int tid = threadIdx.x;
  const int m0 = blockIdx.y * 64;
  const int n0 = blockIdx.x * 64;
#pragma unroll
  for (int i = 0; i < 8; ++i) {      // stage x tile: 64x128 fp32
    int idx = tid + 256 * i;
    int row = idx >> 5, c4 = idx & 31;
    float4 v = *(const float4*)(x + (size_t)(m0 + row) * K + c4 * 4);
    *(float4*)&xs[row][c4 * 4] = v;
  }
#pragma unroll
  for (int i = 0; i < 8; ++i) {      // stage w tile: 128x64 int8
    int idx = tid + 256 * i;
    int k = idx >> 4, c4 = idx & 15;
    *(int*)&wsm[k][c4 * 4] = *(const int*)(w0q + (size_t)k * N + n0 + c4 * 4);
  }
  __syncthreads();
  const int ty = tid >> 4, tx = tid & 15;
  float acc[4][4] = {};
  for (int k4 = 0; k4 < K; k4 += 4) {
    float xr[4][4];
#pragma unroll
    for (int i = 0; i < 4; ++i) {
      float4 v = *(const float4*)&xs[ty * 4 + i][k4];
      xr[i][0] = v.x; xr[i][1] = v.y; xr[i][2] = v.z; xr[i][3] = v.w;
    }
#pragma unroll
    for (int kk = 0; kk < 4; ++kk) {
      char4 cv = *(const char4*)&wsm[k4 + kk][tx * 4];
      float w0 = (float)cv.x, w1 = (float)cv.y, w2 = (float)cv.z, w3 = (float)cv.w;
#pragma unroll
      for (int i = 0; i < 4; ++i) {
        acc[i][0] = fmaf(xr[i][kk], w0, acc[i][0]);
        acc[i][1] = fmaf(xr[i][kk], w1, acc[i][1]);
        acc[i][2] = fmaf(xr[i][kk], w2, acc[i][2]);
        acc[i][3] = fmaf(xr[i][kk], w3, acc[i][3]);
      }
    }
  }
  const int n = n0 + tx * 4;
  float b0v = 2.0f * bint[n + 0], b1v = 2.0f * bint[n + 1];
  float b2v = 2.0f * bint[n + 2], b3v = 2.0f * bint[n + 3];
#pragma unroll
  for (int i = 0; i < 4; ++i) {
    int m = m0 + ty * 4 + i;
    char4 o;
    o.x = qrelu_level(2.0f * acc[i][0] + b0v);
    o.y = qrelu_level(2.0f * acc[i][1] + b1v);
    o.z = qrelu_level(2.0f * acc[i][2] + b2v);
    o.w = qrelu_level(2.0f * acc[i][3] + b3v);
    *(char4*)&a1[(size_t)m * 1024 + n] = o;
  }
}

// ---------------------------------------------------------------- int8 GEMM
// C = A(MxK,int8) * BT(NxK,int8)^T. 128x128 block tile, BK=64, 4 waves (2x2),
// each wave 64x64 via 4x4 MFMA 16x16x64 tiles.
//
// Round-3 change: single-barrier LDS DOUBLE-BUFFER. Tile k+1 is staged into
// buf^1 BEFORE computing tile k from buf^0; the compiler's s_waitcnt vmcnt(0)
// at the (single) barrier then waits on loads that have been in flight for a
// full compute phase (~450 cyc) -> drain ~free, and barrier count halves.
// Int8 keeps dbuf LDS at 32 KB so the m132 occupancy penalty doesn't apply.
//
// LDS bank-swizzle (round 2, kept): chunk kc of row `row` stored at position
// p = (kc + (row>>1)) & 3 within the row's 64B; fragment reads use
// p = (quad + (r>>1)) & 3 -> conflict-free, global coalescing preserved.
//
// FINAL=false: out int8 = clip(round(C/32 + 2*bint),0,63)   (relu-quant level)
// FINAL=true : out fp32 = C/2048 + bint/32
template <bool FINAL>
__global__ __launch_bounds__(256) void gemm_i8(const int8_t* __restrict__ A,
                                               const int8_t* __restrict__ BT,
                                               const float* __restrict__ bint,
                                               void* __restrict__ outp,
                                               int M, int N, int K) {
  __shared__ __align__(16) int8_t ldsA[2][64 * 128];
  __shared__ __align__(16) int8_t ldsB[2][64 * 128];
  const int tid = threadIdx.x;
  const int wid = tid >> 6;
  const int lane = tid & 63;
  const int wm = wid >> 1, wn = wid & 1;
  const int quad = lane >> 4, r = lane & 15;
  const int m0 = blockIdx.y * 128, n0 = blockIdx.x * 128;

  const int8_t* Ab = A + (size_t)m0 * K;
  const int8_t* Bb = BT + (size_t)n0 * K;

  // staging geometry (swizzled): lane covers LDS chunk c = tid (and tid+256);
  // c -> row = c>>2, position p = c&3; fetches global chunk kc = (p - (row>>1)) & 3.
  const int srow = tid >> 2;                       // 0..63 (second async: +64)
  const int sp = tid & 3;
  const int skc = (sp - (srow >> 1)) & 3;          // same for row+64
  const int8_t* gA0 = Ab + (size_t)srow * K + skc * 16;
  const int8_t* gA1 = Ab + (size_t)(srow + 64) * K + skc * 16;
  const int8_t* gB0 = Bb + (size_t)srow * K + skc * 16;
  const int8_t* gB1 = Bb + (size_t)(srow + 64) * K + skc * 16;
  const int ldsOff0 = (wid * 64) * 16;             // wave-uniform; HW adds lane*16
  const int ldsOff1 = (wid * 64 + 256) * 16;

  // fragment-read position within a row's 64B (independent of mt/nt/wm/wn)
  const int pfrag = (quad + (r >> 1)) & 3;

  v4i acc[4][4] = {};

  // prologue: stage tile 0 into buffer 0
  async16(gA0, &ldsA[0][ldsOff0]);
  async16(gA1, &ldsA[0][ldsOff1]);
  async16(gB0, &ldsB[0][ldsOff0]);
  async16(gB1, &ldsB[0][ldsOff1]);
  __syncthreads();

  for (int k0 = 0; k0 < K; k0 += 64) {
    const int p = (k0 >> 6) & 1;
    if (k0 + 64 < K) {   // prefetch next tile into the other buffer (no wait)
      async16(gA0 + k0 + 64, &ldsA[1 - p][ldsOff0]);
      async16(gA1 + k0 + 64, &ldsA[1 - p][ldsOff1]);
      async16(gB0 + k0 + 64, &ldsB[1 - p][ldsOff0]);
      async16(gB1 + k0 + 64, &ldsB[1 - p][ldsOff1]);
    }
    v4i af[4], bf[4];
#pragma unroll
    for (int mt = 0; mt < 4; ++mt)
      af[mt] = *(const v4i*)&ldsA[p][(wm * 64 + mt * 16 + r) * 64 + pfrag * 16];
#pragma unroll
    for (int nt = 0; nt < 4; ++nt)
      bf[nt] = *(const v4i*)&ldsB[p][(wn * 64 + nt * 16 + r) * 64 + pfrag * 16];
#pragma unroll
    for (int mt = 0; mt < 4; ++mt)
#pragma unroll
      for (int nt = 0; nt < 4; ++nt)
        acc[mt][nt] = __builtin_amdgcn_mfma_i32_16x16x64_i8(af[mt], bf[nt],
                                                            acc[mt][nt], 0, 0, 0);
    // single barrier: drains this iter's prefetch (in flight during the MFMAs)
    // and protects buf p against next iter's staging overwrite... (buf p is
    // re-staged two iters out; buf 1-p is read next iter after this barrier)
    __syncthreads();
  }

  const int mbase = m0 + wm * 64;
  const int nbase = n0 + wn * 64;
  if (FINAL) {
    float* out = (float*)outp;
#pragma unroll
    for (int nt = 0; nt < 4; ++nt) {
      int n = nbase + nt * 16 + r;
      float bq = bint[n] * 0.03125f;
#pragma unroll
      for (int mt = 0; mt < 4; ++mt)
#pragma unroll
        for (int g = 0; g < 4; ++g) {
          int m = mbase + mt * 16 + quad * 4 + g;
          out[(size_t)m * N + n] = (float)acc[mt][nt][g] * (1.0f / 2048.0f) + bq;
        }
    }
  } else {
    int8_t* out = (int8_t*)outp;
#pragma unroll
    for (int nt = 0; nt < 4; ++nt) {
      int n = nbase + nt * 16 + r;
      float b2 = 2.0f * bint[n];
#pragma unroll
      for (int mt = 0; mt < 4; ++mt)
#pragma unroll
        for (int g = 0; g < 4; ++g) {
          int m = mbase + mt * 16 + quad * 4 + g;
          // p = C/32 + 2*bint exactly representable in fp32 -> exact half-even ties
          out[(size_t)m * N + n] =
              qrelu_level((float)acc[mt][nt][g] * 0.03125f + b2);
        }
    }
  }
}

// ---------------------------------------------------------------- launch
extern "C" void kernel_launch(void* const* d_in, const int* in_sizes, int n_in,
                              void* d_out, int out_size, void* d_ws, size_t ws_size,
                              hipStream_t stream) {
  const float* x  = (const float*)d_in[0];
  const float* W0 = (const float*)d_in[1];
  const float* b0 = (const float*)d_in[2];
  const float* W1 = (const float*)d_in[3];
  const float* b1 = (const float*)d_in[4];
  const float* W2 = (const float*)d_in[5];
  const float* b2 = (const float*)d_in[6];
  const float* W3 = (const float*)d_in[7];
  const float* b3 = (const float*)d_in[8];

  uint8_t* ws = (uint8_t*)d_ws;
  int8_t* wq0 = (int8_t*)(ws + 0);          // 128x1024 int8   (K-major)
  int8_t* wt1 = (int8_t*)(ws + 131072);     // 2048x1024 int8  (N x K)
  int8_t* wt2 = (int8_t*)(ws + 2228224);    // 4096x2048
  int8_t* wt3 = (int8_t*)(ws + 10616832);   // 4096x4096
  float*  bq0 = (float*)(ws + 27394048);    // 1024 f32 (integer levels)
  float*  bq1 = (float*)(ws + 27398144);    // 2048
  float*  bq2 = (float*)(ws + 27406336);    // 4096
  float*  bq3 = (float*)(ws + 27422720);    // 4096
  int8_t* a1  = (int8_t*)(ws + 27439104);   // 8192x1024 int8
  int8_t* a2  = (int8_t*)(ws + 35827712);   // 8192x2048
  int8_t* a3  = (int8_t*)(ws + 52604928);   // 8192x4096  (ends at 86159360 B)

  quant_w0_k<<<128, 256, 0, stream>>>(W0, wq0);
  quantT_k<<<dim3(2048 / 64, 1024 / 64), 256, 0, stream>>>(W1, wt1, 1024, 2048);
  quantT_k<<<dim3(4096 / 64, 2048 / 64), 256, 0, stream>>>(W2, wt2, 2048, 4096);
  quantT_k<<<dim3(4096 / 64, 4096 / 64), 256, 0, stream>>>(W3, wt3, 4096, 4096);
  quant_bias_k<<<16, 256, 0, stream>>>(b0, b1, b2, b3, bq0, bq1, bq2, bq3);
  layer0_k<<<dim3(16, 128), 256, 0, stream>>>(x, wq0, bq0, a1);
  gemm_i8<false><<<dim3(16, 64), 256, 0, stream>>>(a1, wt1, bq1, a2, 8192, 2048, 1024);
  gemm_i8<false><<<dim3(32, 64), 256, 0, stream>>>(a2, wt2, bq2, a3, 8192, 4096, 2048);
  gemm_i8<true><<<dim3(32, 64), 256, 0, stream>>>(a3, wt3, bq3, d_out, 8192, 4096, 4096);
}